// Round 2
// baseline (1025.204 us; speedup 1.0000x reference)
//
#include <hip/hip_runtime.h>
#include <cstddef>

#define NN 100000
#define NE 1600000
#define NBLK 98   // ceil(NN / 1024)

// Pin a float2 into VGPRs: the empty asm is opaque, so the compiler cannot
// rematerialize (re-load) the value inside the loop body.
#define PIN2(v) asm volatile("" : "+v"((v).x), "+v"((v).y))

// ===========================================================================
// CSR build: histogram(dst) -> hierarchical exclusive scan -> scatter
// ===========================================================================
__global__ __launch_bounds__(256) void hist_dst(const int* __restrict__ ei,
                                                int* __restrict__ deg)
{
    int i = blockIdx.x * 256 + threadIdx.x;
    int stride = gridDim.x * 256;
    for (int e = i; e < NE; e += stride)
        atomicAdd(&deg[ei[NE + e]], 1);
}

// Stage 1: per-block (1024 elems) sum of degrees
__global__ __launch_bounds__(1024) void deg_block_sum(const int* __restrict__ deg,
                                                      int* __restrict__ bsum)
{
    __shared__ int s[16];
    int t = threadIdx.x;
    int i = blockIdx.x * 1024 + t;
    int v = (i < NN) ? deg[i] : 0;
    #pragma unroll
    for (int o = 32; o > 0; o >>= 1) v += __shfl_down(v, o, 64);
    if ((t & 63) == 0) s[t >> 6] = v;
    __syncthreads();
    if (t < 64) {
        int w = (t < 16) ? s[t] : 0;
        #pragma unroll
        for (int o = 8; o > 0; o >>= 1) w += __shfl_down(w, o, 64);
        if (t == 0) bsum[blockIdx.x] = w;
    }
}

// Stage 2: exclusive scan of the 98 block sums (single tiny block);
// also writes off[NN] = total edge count.
__global__ __launch_bounds__(128) void scan_bsum(int* __restrict__ bsum,
                                                 int* __restrict__ off)
{
    __shared__ int s[128];
    int t = threadIdx.x;
    int v = (t < NBLK) ? bsum[t] : 0;
    s[t] = v;
    __syncthreads();
    #pragma unroll
    for (int o = 1; o < 128; o <<= 1) {
        int u = (t >= o) ? s[t - o] : 0;
        __syncthreads();
        s[t] += u;
        __syncthreads();
    }
    if (t < NBLK) bsum[t] = s[t] - v;   // exclusive block offset
    if (t == 127) off[NN] = s[127];     // grand total
}

// Stage 3: per-block exclusive scan + block offset. Writes off[i] and
// rewrites deg[i] = off[i] (deg then serves as the scatter cursor).
__global__ __launch_bounds__(1024) void deg_block_scan(int* __restrict__ deg,
                                                       int* __restrict__ off,
                                                       const int* __restrict__ bsum)
{
    __shared__ int s[1024];
    int t = threadIdx.x;
    int i = blockIdx.x * 1024 + t;
    int v = (i < NN) ? deg[i] : 0;
    s[t] = v;
    __syncthreads();
    #pragma unroll
    for (int o = 1; o < 1024; o <<= 1) {
        int u = (t >= o) ? s[t - o] : 0;
        __syncthreads();
        s[t] += u;
        __syncthreads();
    }
    int excl = s[t] - v + bsum[blockIdx.x];
    if (i < NN) { off[i] = excl; deg[i] = excl; }
}

__global__ __launch_bounds__(256) void scatter_perm(const int* __restrict__ ei,
                                                    int* __restrict__ cur,
                                                    int2* __restrict__ perm2)
{
    int i = blockIdx.x * 256 + threadIdx.x;
    int stride = gridDim.x * 256;
    for (int e = i; e < NE; e += stride) {
        int s = ei[e];
        int d = ei[NE + e];
        int pos = atomicAdd(&cur[d], 1);
        perm2[pos] = make_int2(e, s);
    }
}

// ===========================================================================
// conv1 gather: one FULL wave per node (node is wave-uniform =>
// readfirstlane is legal). 2 channels/lane (128 ch).
// Weights held in registers, PINNED via empty asm so the compiler cannot
// rematerialize the loads inside the edge loop (VGPR=28 pathology).
// 2-deep data prefetch, 3-deep record prefetch; indices clamped to j1-1.
// aggr1[n] = sum_{e: dst=n} relu(x[src_e] + ea[e] @ We1 + be1)
// ===========================================================================
__global__ __launch_bounds__(256) void conv1_gather(
    const float* __restrict__ x, const float* __restrict__ ea,
    const float* __restrict__ We, const float* __restrict__ be,
    const int* __restrict__ off, const int2* __restrict__ perm2,
    float* __restrict__ aggr)
{
    int t = threadIdx.x;
    int lane = t & 63;
    int n = blockIdx.x * 4 + (t >> 6);
    if (n >= NN) return;

    // per-lane weight column pair: rw[k] = We[k][2*lane .. 2*lane+1]
    const float2* W2 = (const float2*)We;
    float2 rw[16];
    #pragma unroll
    for (int k = 0; k < 16; k++) rw[k] = W2[(k << 6) + lane];
    float2 bias = ((const float2*)be)[lane];
    #pragma unroll
    for (int k = 0; k < 16; k++) PIN2(rw[k]);
    PIN2(bias);

    int j0 = off[n], j1 = off[n + 1];
    float2 acc = make_float2(0.f, 0.f);

    if (j0 < j1) {
        int last = j1 - 1;
        int2 r0 = perm2[j0];
        int2 r1 = perm2[min(j0 + 1, last)];
        int2 r2 = perm2[min(j0 + 2, last)];

        int e0 = __builtin_amdgcn_readfirstlane(r0.x);
        int s0 = __builtin_amdgcn_readfirstlane(r0.y);
        const float4* apA = (const float4*)(ea + (size_t)e0 * 16);
        float4 a0 = apA[0], a1 = apA[1], a2 = apA[2], a3 = apA[3];
        float2 xA = *(const float2*)(x + (size_t)s0 * 128 + (lane << 1));

        int e1 = __builtin_amdgcn_readfirstlane(r1.x);
        int s1 = __builtin_amdgcn_readfirstlane(r1.y);
        const float4* apB = (const float4*)(ea + (size_t)e1 * 16);
        float4 b0 = apB[0], b1 = apB[1], b2 = apB[2], b3 = apB[3];
        float2 xB = *(const float2*)(x + (size_t)s1 * 128 + (lane << 1));

        #pragma unroll 2
        for (int j = j0; j < j1; j++) {
            // issue stage C (data for j+2, clamped) + record j+3 (clamped)
            int e2 = __builtin_amdgcn_readfirstlane(r2.x);
            int s2 = __builtin_amdgcn_readfirstlane(r2.y);
            const float4* apC = (const float4*)(ea + (size_t)e2 * 16);
            float4 c0 = apC[0], c1 = apC[1], c2 = apC[2], c3 = apC[3];
            float2 xC = *(const float2*)(x + (size_t)s2 * 128 + (lane << 1));
            int2 r3 = perm2[min(j + 3, last)];

            // compute stage A (edge j)
            float av[16] = {a0.x,a0.y,a0.z,a0.w, a1.x,a1.y,a1.z,a1.w,
                            a2.x,a2.y,a2.z,a2.w, a3.x,a3.y,a3.z,a3.w};
            float2 m = bias;
            #pragma unroll
            for (int k = 0; k < 16; k++) {
                m.x = fmaf(av[k], rw[k].x, m.x);
                m.y = fmaf(av[k], rw[k].y, m.y);
            }
            acc.x += fmaxf(xA.x + m.x, 0.0f);
            acc.y += fmaxf(xA.y + m.y, 0.0f);

            // rotate A <= B <= C
            a0 = b0; a1 = b1; a2 = b2; a3 = b3; xA = xB;
            b0 = c0; b1 = c1; b2 = c2; b3 = c3; xB = xC;
            r2 = r3;
        }
    }
    *(float2*)(aggr + (size_t)n * 128 + (lane << 1)) = acc;
}

// ===========================================================================
// conv_mu + conv_logstd gather, fused: one FULL wave per node. Trees split
// across the wave: lanes 0-31 = mu (W2), lanes 32-63 = logstd (W3),
// 2 channels/lane. Pinned register weights + same deep pipeline as conv1.
// ===========================================================================
__global__ __launch_bounds__(256) void conv23_gather(
    const float* __restrict__ h, const float* __restrict__ ea,
    const float* __restrict__ We2, const float* __restrict__ be2,
    const float* __restrict__ We3, const float* __restrict__ be3,
    const int* __restrict__ off, const int2* __restrict__ perm2,
    float* __restrict__ aggr2, float* __restrict__ aggr3)
{
    int t = threadIdx.x;
    int lane = t & 63;
    int half = lane >> 5;            // 0 = mu tree, 1 = logstd tree
    int cl = lane & 31;
    int c2 = cl << 1;                // channel pair within the tree
    int n = blockIdx.x * 4 + (t >> 6);
    if (n >= NN) return;

    const float2* Wp = (const float2*)(half ? We3 : We2);
    const float2* bp = (const float2*)(half ? be3 : be2);
    float2 rw[16];
    #pragma unroll
    for (int k = 0; k < 16; k++) rw[k] = Wp[(k << 5) + cl];
    float2 bias = bp[cl];
    #pragma unroll
    for (int k = 0; k < 16; k++) PIN2(rw[k]);
    PIN2(bias);

    int j0 = off[n], j1 = off[n + 1];
    float2 acc = make_float2(0.f, 0.f);

    if (j0 < j1) {
        int last = j1 - 1;
        int2 r0 = perm2[j0];
        int2 r1 = perm2[min(j0 + 1, last)];
        int2 r2 = perm2[min(j0 + 2, last)];

        int e0 = __builtin_amdgcn_readfirstlane(r0.x);
        int s0 = __builtin_amdgcn_readfirstlane(r0.y);
        const float4* apA = (const float4*)(ea + (size_t)e0 * 16);
        float4 a0 = apA[0], a1 = apA[1], a2 = apA[2], a3 = apA[3];
        float2 hA = *(const float2*)(h + (size_t)s0 * 64 + c2);

        int e1 = __builtin_amdgcn_readfirstlane(r1.x);
        int s1 = __builtin_amdgcn_readfirstlane(r1.y);
        const float4* apB = (const float4*)(ea + (size_t)e1 * 16);
        float4 b0 = apB[0], b1 = apB[1], b2 = apB[2], b3 = apB[3];
        float2 hB = *(const float2*)(h + (size_t)s1 * 64 + c2);

        #pragma unroll 2
        for (int j = j0; j < j1; j++) {
            int e2 = __builtin_amdgcn_readfirstlane(r2.x);
            int s2 = __builtin_amdgcn_readfirstlane(r2.y);
            const float4* apC = (const float4*)(ea + (size_t)e2 * 16);
            float4 c0 = apC[0], c1 = apC[1], c2v = apC[2], c3 = apC[3];
            float2 hC = *(const float2*)(h + (size_t)s2 * 64 + c2);
            int2 r3 = perm2[min(j + 3, last)];

            float av[16] = {a0.x,a0.y,a0.z,a0.w, a1.x,a1.y,a1.z,a1.w,
                            a2.x,a2.y,a2.z,a2.w, a3.x,a3.y,a3.z,a3.w};
            float2 m = bias;
            #pragma unroll
            for (int k = 0; k < 16; k++) {
                m.x = fmaf(av[k], rw[k].x, m.x);
                m.y = fmaf(av[k], rw[k].y, m.y);
            }
            acc.x += fmaxf(hA.x + m.x, 0.0f);
            acc.y += fmaxf(hA.y + m.y, 0.0f);

            a0 = b0; a1 = b1; a2 = b2; a3 = b3; hA = hB;
            b0 = c0; b1 = c1; b2 = c2v; b3 = c3; hB = hC;
            r2 = r3;
        }
    }
    float* dstp = (half ? aggr3 : aggr2) + (size_t)n * 64 + c2;
    *(float2*)dstp = acc;
}

// ===========================================================================
// Node MLP: out = epilogue( relu((xin+aggr) @ Wa + ba) @ Wb + bb )
// KIN -> 64 -> 64. 64 nodes per block, 256 threads, 4x4 register tiles.
// mode: 0 = none, 1 = relu, 2 = clip(-10, 10)
// ===========================================================================
template <int KIN>
__global__ __launch_bounds__(256) void node_mlp(
    const float* __restrict__ xin, const float* __restrict__ aggr,
    const float* __restrict__ Wa, const float* __restrict__ ba,
    const float* __restrict__ Wb, const float* __restrict__ bb,
    float* __restrict__ out, int mode)
{
    constexpr int S0 = KIN + 4;
    constexpr int K4 = KIN / 4;
    __shared__ float sWa[KIN * 64];
    __shared__ float sWb[64 * 64];
    __shared__ float sh[64 * S0];
    __shared__ float sba[64], sbb[64];
    int t = threadIdx.x;
    for (int i = t; i < KIN * 16; i += 256) ((float4*)sWa)[i] = ((const float4*)Wa)[i];
    for (int i = t; i < 1024; i += 256)     ((float4*)sWb)[i] = ((const float4*)Wb)[i];
    if (t < 64) { sba[t] = ba[t]; sbb[t] = bb[t]; }

    int nb = blockIdx.x << 6;
    for (int i = t; i < 64 * K4; i += 256) {
        int n = i / K4, k4 = i % K4;
        int node = nb + n;
        float4 v = make_float4(0.f, 0.f, 0.f, 0.f);
        if (node < NN) {
            float4 a = ((const float4*)(xin  + (size_t)node * KIN))[k4];
            float4 b = ((const float4*)(aggr + (size_t)node * KIN))[k4];
            v = make_float4(a.x + b.x, a.y + b.y, a.z + b.z, a.w + b.w);
        }
        *(float4*)&sh[n * S0 + (k4 << 2)] = v;
    }
    __syncthreads();

    int tx = t & 15, ty = t >> 4;
    int c0 = tx << 2, n0 = ty << 2;

    float4 b1 = *(const float4*)&sba[c0];
    float acc[4][4];
    #pragma unroll
    for (int i = 0; i < 4; i++) { acc[i][0] = b1.x; acc[i][1] = b1.y; acc[i][2] = b1.z; acc[i][3] = b1.w; }
    for (int k4 = 0; k4 < K4; k4++) {
        int k = k4 << 2;
        float4 w0 = *(const float4*)&sWa[((k + 0) << 6) + c0];
        float4 w1 = *(const float4*)&sWa[((k + 1) << 6) + c0];
        float4 w2 = *(const float4*)&sWa[((k + 2) << 6) + c0];
        float4 w3 = *(const float4*)&sWa[((k + 3) << 6) + c0];
        #pragma unroll
        for (int i = 0; i < 4; i++) {
            float4 hv = *(const float4*)&sh[(n0 + i) * S0 + k];
            acc[i][0] = fmaf(hv.x, w0.x, acc[i][0]); acc[i][1] = fmaf(hv.x, w0.y, acc[i][1]);
            acc[i][2] = fmaf(hv.x, w0.z, acc[i][2]); acc[i][3] = fmaf(hv.x, w0.w, acc[i][3]);
            acc[i][0] = fmaf(hv.y, w1.x, acc[i][0]); acc[i][1] = fmaf(hv.y, w1.y, acc[i][1]);
            acc[i][2] = fmaf(hv.y, w1.z, acc[i][2]); acc[i][3] = fmaf(hv.y, w1.w, acc[i][3]);
            acc[i][0] = fmaf(hv.z, w2.x, acc[i][0]); acc[i][1] = fmaf(hv.z, w2.y, acc[i][1]);
            acc[i][2] = fmaf(hv.z, w2.z, acc[i][2]); acc[i][3] = fmaf(hv.z, w2.w, acc[i][3]);
            acc[i][0] = fmaf(hv.w, w3.x, acc[i][0]); acc[i][1] = fmaf(hv.w, w3.y, acc[i][1]);
            acc[i][2] = fmaf(hv.w, w3.z, acc[i][2]); acc[i][3] = fmaf(hv.w, w3.w, acc[i][3]);
        }
    }
    __syncthreads();
    #pragma unroll
    for (int i = 0; i < 4; i++) {
        float4 v = make_float4(fmaxf(acc[i][0], 0.f), fmaxf(acc[i][1], 0.f),
                               fmaxf(acc[i][2], 0.f), fmaxf(acc[i][3], 0.f));
        *(float4*)&sh[(n0 + i) * 68 + c0] = v;
    }
    __syncthreads();

    float4 b2 = *(const float4*)&sbb[c0];
    float acc2[4][4];
    #pragma unroll
    for (int i = 0; i < 4; i++) { acc2[i][0] = b2.x; acc2[i][1] = b2.y; acc2[i][2] = b2.z; acc2[i][3] = b2.w; }
    for (int k4 = 0; k4 < 16; k4++) {
        int k = k4 << 2;
        float4 w0 = *(const float4*)&sWb[((k + 0) << 6) + c0];
        float4 w1 = *(const float4*)&sWb[((k + 1) << 6) + c0];
        float4 w2 = *(const float4*)&sWb[((k + 2) << 6) + c0];
        float4 w3 = *(const float4*)&sWb[((k + 3) << 6) + c0];
        #pragma unroll
        for (int i = 0; i < 4; i++) {
            float4 hv = *(const float4*)&sh[(n0 + i) * 68 + k];
            acc2[i][0] = fmaf(hv.x, w0.x, acc2[i][0]); acc2[i][1] = fmaf(hv.x, w0.y, acc2[i][1]);
            acc2[i][2] = fmaf(hv.x, w0.z, acc2[i][2]); acc2[i][3] = fmaf(hv.x, w0.w, acc2[i][3]);
            acc2[i][0] = fmaf(hv.y, w1.x, acc2[i][0]); acc2[i][1] = fmaf(hv.y, w1.y, acc2[i][1]);
            acc2[i][2] = fmaf(hv.y, w1.z, acc2[i][2]); acc2[i][3] = fmaf(hv.y, w1.w, acc2[i][3]);
            acc2[i][0] = fmaf(hv.z, w2.x, acc2[i][0]); acc2[i][1] = fmaf(hv.z, w2.y, acc2[i][1]);
            acc2[i][2] = fmaf(hv.z, w2.z, acc2[i][2]); acc2[i][3] = fmaf(hv.z, w2.w, acc2[i][3]);
            acc2[i][0] = fmaf(hv.w, w3.x, acc2[i][0]); acc2[i][1] = fmaf(hv.w, w3.y, acc2[i][1]);
            acc2[i][2] = fmaf(hv.w, w3.z, acc2[i][2]); acc2[i][3] = fmaf(hv.w, w3.w, acc2[i][3]);
        }
    }

    #pragma unroll
    for (int i = 0; i < 4; i++) {
        int node = nb + n0 + i;
        if (node >= NN) continue;
        float4 v = make_float4(acc2[i][0], acc2[i][1], acc2[i][2], acc2[i][3]);
        if (mode == 1) {
            v = make_float4(fmaxf(v.x, 0.f), fmaxf(v.y, 0.f), fmaxf(v.z, 0.f), fmaxf(v.w, 0.f));
        } else if (mode == 2) {
            v = make_float4(fminf(fmaxf(v.x, -10.f), 10.f), fminf(fmaxf(v.y, -10.f), 10.f),
                            fminf(fmaxf(v.z, -10.f), 10.f), fminf(fmaxf(v.w, -10.f), 10.f));
        }
        *(float4*)(out + (size_t)node * 64 + c0) = v;
    }
}

extern "C" void kernel_launch(void* const* d_in, const int* in_sizes, int n_in,
                              void* d_out, int out_size, void* d_ws, size_t ws_size,
                              hipStream_t stream)
{
    const float* x   = (const float*)d_in[0];
    const int*   ei  = (const int*)  d_in[1];
    const float* ea  = (const float*)d_in[2];
    const float* We1 = (const float*)d_in[3];
    const float* be1 = (const float*)d_in[4];
    const float* W1a = (const float*)d_in[5];
    const float* b1a = (const float*)d_in[6];
    const float* W1b = (const float*)d_in[7];
    const float* b1b = (const float*)d_in[8];
    const float* We2 = (const float*)d_in[9];
    const float* be2 = (const float*)d_in[10];
    const float* W2a = (const float*)d_in[11];
    const float* b2a = (const float*)d_in[12];
    const float* W2b = (const float*)d_in[13];
    const float* b2b = (const float*)d_in[14];
    const float* We3 = (const float*)d_in[15];
    const float* be3 = (const float*)d_in[16];
    const float* W3a = (const float*)d_in[17];
    const float* b3a = (const float*)d_in[18];
    const float* W3b = (const float*)d_in[19];
    const float* b3b = (const float*)d_in[20];

    float* out = (float*)d_out;
    float* ws = (float*)d_ws;
    // float scratch: aggr1 [12.8M] (later aliased by aggr2/aggr3), h [6.4M]
    float* aggr1 = ws;
    float* h     = ws + 12800000;
    float* aggr2 = ws;              // aliases aggr1 (dead after node_mlp<128>)
    float* aggr3 = ws + 6400000;
    // int scratch after 19.2M floats: off [NN+1], cur [NN], perm2 [2*NE]
    int* ibase = (int*)(ws + 19200000);
    int* off   = ibase;
    int* cur   = ibase + (NN + 1);
    int2* perm2 = (int2*)(ibase + (2 * NN + 2));
    // 98 block sums live in the (currently idle) aggr3 float region —
    // CSR build completes before any conv kernel touches aggr3.
    int* bsum  = (int*)(ws + 6400000);

    // ---- CSR build (shared by conv1 and conv23) ----
    hipMemsetAsync(cur, 0, (size_t)NN * sizeof(int), stream);
    hist_dst<<<2048, 256, 0, stream>>>(ei, cur);
    deg_block_sum<<<NBLK, 1024, 0, stream>>>(cur, bsum);
    scan_bsum<<<1, 128, 0, stream>>>(bsum, off);
    deg_block_scan<<<NBLK, 1024, 0, stream>>>(cur, off, bsum); // cur -> cursor
    scatter_perm<<<2048, 256, 0, stream>>>(ei, cur, perm2);

    // ---- layer 1 ----
    conv1_gather<<<(NN + 3) / 4, 256, 0, stream>>>(x, ea, We1, be1, off, perm2, aggr1);
    node_mlp<128><<<(NN + 63) / 64, 256, 0, stream>>>(x, aggr1, W1a, b1a, W1b, b1b, h, 1);

    // ---- layers 2+3 (fused edge pass) ----
    conv23_gather<<<(NN + 3) / 4, 256, 0, stream>>>(h, ea, We2, be2, We3, be3,
                                                    off, perm2, aggr2, aggr3);
    node_mlp<64><<<(NN + 63) / 64, 256, 0, stream>>>(h, aggr2, W2a, b2a, W2b, b2b, out, 0);
    node_mlp<64><<<(NN + 63) / 64, 256, 0, stream>>>(h, aggr3, W3a, b3a, W3b, b3b,
                                                     out + (size_t)NN * 64, 2);
}

// Round 3
// 993.872 us; speedup vs baseline: 1.0315x; 1.0315x over previous
//
#include <hip/hip_runtime.h>
#include <cstddef>

#define NN 100000
#define NE 1600000
#define NBLK 98   // ceil(NN / 1024)

// ===========================================================================
// CSR build: histogram(dst) -> hierarchical exclusive scan -> scatter
// ===========================================================================
__global__ __launch_bounds__(256) void hist_dst(const int* __restrict__ ei,
                                                int* __restrict__ deg)
{
    int i = blockIdx.x * 256 + threadIdx.x;
    int stride = gridDim.x * 256;
    for (int e = i; e < NE; e += stride)
        atomicAdd(&deg[ei[NE + e]], 1);
}

// Stage 1: per-block (1024 elems) sum of degrees
__global__ __launch_bounds__(1024) void deg_block_sum(const int* __restrict__ deg,
                                                      int* __restrict__ bsum)
{
    __shared__ int s[16];
    int t = threadIdx.x;
    int i = blockIdx.x * 1024 + t;
    int v = (i < NN) ? deg[i] : 0;
    #pragma unroll
    for (int o = 32; o > 0; o >>= 1) v += __shfl_down(v, o, 64);
    if ((t & 63) == 0) s[t >> 6] = v;
    __syncthreads();
    if (t < 64) {
        int w = (t < 16) ? s[t] : 0;
        #pragma unroll
        for (int o = 8; o > 0; o >>= 1) w += __shfl_down(w, o, 64);
        if (t == 0) bsum[blockIdx.x] = w;
    }
}

// Stage 2: exclusive scan of the 98 block sums (single tiny block);
// also writes off[NN] = total edge count.
__global__ __launch_bounds__(128) void scan_bsum(int* __restrict__ bsum,
                                                 int* __restrict__ off)
{
    __shared__ int s[128];
    int t = threadIdx.x;
    int v = (t < NBLK) ? bsum[t] : 0;
    s[t] = v;
    __syncthreads();
    #pragma unroll
    for (int o = 1; o < 128; o <<= 1) {
        int u = (t >= o) ? s[t - o] : 0;
        __syncthreads();
        s[t] += u;
        __syncthreads();
    }
    if (t < NBLK) bsum[t] = s[t] - v;   // exclusive block offset
    if (t == 127) off[NN] = s[127];     // grand total
}

// Stage 3: per-block exclusive scan + block offset. Writes off[i] and
// rewrites deg[i] = off[i] (deg then serves as the scatter cursor).
__global__ __launch_bounds__(1024) void deg_block_scan(int* __restrict__ deg,
                                                       int* __restrict__ off,
                                                       const int* __restrict__ bsum)
{
    __shared__ int s[1024];
    int t = threadIdx.x;
    int i = blockIdx.x * 1024 + t;
    int v = (i < NN) ? deg[i] : 0;
    s[t] = v;
    __syncthreads();
    #pragma unroll
    for (int o = 1; o < 1024; o <<= 1) {
        int u = (t >= o) ? s[t - o] : 0;
        __syncthreads();
        s[t] += u;
        __syncthreads();
    }
    int excl = s[t] - v + bsum[blockIdx.x];
    if (i < NN) { off[i] = excl; deg[i] = excl; }
}

__global__ __launch_bounds__(256) void scatter_perm(const int* __restrict__ ei,
                                                    int* __restrict__ cur,
                                                    int2* __restrict__ perm2)
{
    int i = blockIdx.x * 256 + threadIdx.x;
    int stride = gridDim.x * 256;
    for (int e = i; e < NE; e += stride) {
        int s = ei[e];
        int d = ei[NE + e];
        int pos = atomicAdd(&cur[d], 1);
        perm2[pos] = make_int2(e, s);
    }
}

// ===========================================================================
// conv1 gather: one FULL wave per node, 2 channels/lane (128 ch).
// __launch_bounds__(256,6): 6 blocks/CU target raises the VGPR budget to
// ~84 so the 32-float per-lane weight block stays RESIDENT in VGPRs
// (plain (256) targeted 8 waves/EU => 28 VGPRs => weights shuttled through
// AGPR/L1 every edge = ~65 extra VALU ops/edge, the round-1/2 ceiling).
// Processes 2 edges per iteration sharing one rw[] read; edge indices are
// wave-uniform (readfirstlane'd j) so records + edge-attr rows take the
// scalar-memory path. 1 pair prefetched ahead.
// aggr1[n] = sum_{e: dst=n} relu(x[src_e] + ea[e] @ We1 + be1)
// ===========================================================================
__global__ __launch_bounds__(256, 6) void conv1_gather(
    const float* __restrict__ x, const float* __restrict__ ea,
    const float* __restrict__ We, const float* __restrict__ be,
    const int* __restrict__ off, const int2* __restrict__ perm2,
    float* __restrict__ aggr)
{
    int t = threadIdx.x;
    int lane = t & 63;
    int n = blockIdx.x * 4 + (t >> 6);
    if (n >= NN) return;

    // per-lane weight column pair: rw[k] = We[k][2*lane .. 2*lane+1]
    const float2* W2 = (const float2*)We;
    float2 rw[16];
    #pragma unroll
    for (int k = 0; k < 16; k++) rw[k] = W2[(k << 6) + lane];
    float2 bias = ((const float2*)be)[lane];

    int j0 = __builtin_amdgcn_readfirstlane(off[n]);
    int j1 = __builtin_amdgcn_readfirstlane(off[n + 1]);
    float2 acc = make_float2(0.f, 0.f);

    if (j0 < j1) {
        int last = j1 - 1;
        // ---- prefetch pair (j0, j0+1 clamped) ----
        int2 rA = perm2[j0];
        int2 rB = perm2[min(j0 + 1, last)];
        int eA = __builtin_amdgcn_readfirstlane(rA.x);
        int sA = __builtin_amdgcn_readfirstlane(rA.y);
        int eB = __builtin_amdgcn_readfirstlane(rB.x);
        int sB = __builtin_amdgcn_readfirstlane(rB.y);
        const float4* pA = (const float4*)(ea + (size_t)eA * 16);
        const float4* pB = (const float4*)(ea + (size_t)eB * 16);
        float4 A0 = pA[0], A1 = pA[1], A2 = pA[2], A3 = pA[3];
        float4 B0 = pB[0], B1 = pB[1], B2 = pB[2], B3 = pB[3];
        float2 xA = *(const float2*)(x + (size_t)sA * 128 + (lane << 1));
        float2 xB = *(const float2*)(x + (size_t)sB * 128 + (lane << 1));

        for (int j = j0; j < j1; j += 2) {
            int jn = j + 2;
            float4 C0, C1, C2, C3, D0, D1, D2, D3;
            float2 xC, xD;
            if (jn < j1) {   // wave-uniform branch
                int2 rC = perm2[jn];
                int2 rD = perm2[min(jn + 1, last)];
                int eC = __builtin_amdgcn_readfirstlane(rC.x);
                int sC = __builtin_amdgcn_readfirstlane(rC.y);
                int eD = __builtin_amdgcn_readfirstlane(rD.x);
                int sD = __builtin_amdgcn_readfirstlane(rD.y);
                const float4* pC = (const float4*)(ea + (size_t)eC * 16);
                const float4* pD = (const float4*)(ea + (size_t)eD * 16);
                C0 = pC[0]; C1 = pC[1]; C2 = pC[2]; C3 = pC[3];
                D0 = pD[0]; D1 = pD[1]; D2 = pD[2]; D3 = pD[3];
                xC = *(const float2*)(x + (size_t)sC * 128 + (lane << 1));
                xD = *(const float2*)(x + (size_t)sD * 128 + (lane << 1));
            }
            // ---- compute edges j (A) and j+1 (B), sharing rw[k] reads ----
            float avA[16] = {A0.x,A0.y,A0.z,A0.w, A1.x,A1.y,A1.z,A1.w,
                             A2.x,A2.y,A2.z,A2.w, A3.x,A3.y,A3.z,A3.w};
            float avB[16] = {B0.x,B0.y,B0.z,B0.w, B1.x,B1.y,B1.z,B1.w,
                             B2.x,B2.y,B2.z,B2.w, B3.x,B3.y,B3.z,B3.w};
            float2 mA = bias, mB = bias;
            #pragma unroll
            for (int k = 0; k < 16; k++) {
                float2 w = rw[k];
                mA.x = fmaf(avA[k], w.x, mA.x);
                mA.y = fmaf(avA[k], w.y, mA.y);
                mB.x = fmaf(avB[k], w.x, mB.x);
                mB.y = fmaf(avB[k], w.y, mB.y);
            }
            acc.x += fmaxf(xA.x + mA.x, 0.0f);
            acc.y += fmaxf(xA.y + mA.y, 0.0f);
            if (j + 1 < j1) {   // wave-uniform: odd-degree tail guard
                acc.x += fmaxf(xB.x + mB.x, 0.0f);
                acc.y += fmaxf(xB.y + mB.y, 0.0f);
            }
            // rotate (dead on final iteration)
            A0 = C0; A1 = C1; A2 = C2; A3 = C3; xA = xC;
            B0 = D0; B1 = D1; B2 = D2; B3 = D3; xB = xD;
        }
    }
    *(float2*)(aggr + (size_t)n * 128 + (lane << 1)) = acc;
}

// ===========================================================================
// conv_mu + conv_logstd gather, fused: one FULL wave per node. Trees split
// across the wave: lanes 0-31 = mu (W2), lanes 32-63 = logstd (W3),
// 2 channels/lane. Same structure as conv1_gather v3.
// ===========================================================================
__global__ __launch_bounds__(256, 6) void conv23_gather(
    const float* __restrict__ h, const float* __restrict__ ea,
    const float* __restrict__ We2, const float* __restrict__ be2,
    const float* __restrict__ We3, const float* __restrict__ be3,
    const int* __restrict__ off, const int2* __restrict__ perm2,
    float* __restrict__ aggr2, float* __restrict__ aggr3)
{
    int t = threadIdx.x;
    int lane = t & 63;
    int half = lane >> 5;            // 0 = mu tree, 1 = logstd tree
    int cl = lane & 31;
    int co = cl << 1;                // channel pair within the tree
    int n = blockIdx.x * 4 + (t >> 6);
    if (n >= NN) return;

    const float2* Wp = (const float2*)(half ? We3 : We2);
    const float2* bp = (const float2*)(half ? be3 : be2);
    float2 rw[16];
    #pragma unroll
    for (int k = 0; k < 16; k++) rw[k] = Wp[(k << 5) + cl];
    float2 bias = bp[cl];

    int j0 = __builtin_amdgcn_readfirstlane(off[n]);
    int j1 = __builtin_amdgcn_readfirstlane(off[n + 1]);
    float2 acc = make_float2(0.f, 0.f);

    if (j0 < j1) {
        int last = j1 - 1;
        int2 rA = perm2[j0];
        int2 rB = perm2[min(j0 + 1, last)];
        int eA = __builtin_amdgcn_readfirstlane(rA.x);
        int sA = __builtin_amdgcn_readfirstlane(rA.y);
        int eB = __builtin_amdgcn_readfirstlane(rB.x);
        int sB = __builtin_amdgcn_readfirstlane(rB.y);
        const float4* pA = (const float4*)(ea + (size_t)eA * 16);
        const float4* pB = (const float4*)(ea + (size_t)eB * 16);
        float4 A0 = pA[0], A1 = pA[1], A2 = pA[2], A3 = pA[3];
        float4 B0 = pB[0], B1 = pB[1], B2 = pB[2], B3 = pB[3];
        float2 hA = *(const float2*)(h + (size_t)sA * 64 + co);
        float2 hB = *(const float2*)(h + (size_t)sB * 64 + co);

        for (int j = j0; j < j1; j += 2) {
            int jn = j + 2;
            float4 C0, C1, C2, C3, D0, D1, D2, D3;
            float2 hC, hD;
            if (jn < j1) {
                int2 rC = perm2[jn];
                int2 rD = perm2[min(jn + 1, last)];
                int eC = __builtin_amdgcn_readfirstlane(rC.x);
                int sC = __builtin_amdgcn_readfirstlane(rC.y);
                int eD = __builtin_amdgcn_readfirstlane(rD.x);
                int sD = __builtin_amdgcn_readfirstlane(rD.y);
                const float4* pC = (const float4*)(ea + (size_t)eC * 16);
                const float4* pD = (const float4*)(ea + (size_t)eD * 16);
                C0 = pC[0]; C1 = pC[1]; C2 = pC[2]; C3 = pC[3];
                D0 = pD[0]; D1 = pD[1]; D2 = pD[2]; D3 = pD[3];
                hC = *(const float2*)(h + (size_t)sC * 64 + co);
                hD = *(const float2*)(h + (size_t)sD * 64 + co);
            }
            float avA[16] = {A0.x,A0.y,A0.z,A0.w, A1.x,A1.y,A1.z,A1.w,
                             A2.x,A2.y,A2.z,A2.w, A3.x,A3.y,A3.z,A3.w};
            float avB[16] = {B0.x,B0.y,B0.z,B0.w, B1.x,B1.y,B1.z,B1.w,
                             B2.x,B2.y,B2.z,B2.w, B3.x,B3.y,B3.z,B3.w};
            float2 mA = bias, mB = bias;
            #pragma unroll
            for (int k = 0; k < 16; k++) {
                float2 w = rw[k];
                mA.x = fmaf(avA[k], w.x, mA.x);
                mA.y = fmaf(avA[k], w.y, mA.y);
                mB.x = fmaf(avB[k], w.x, mB.x);
                mB.y = fmaf(avB[k], w.y, mB.y);
            }
            acc.x += fmaxf(hA.x + mA.x, 0.0f);
            acc.y += fmaxf(hA.y + mA.y, 0.0f);
            if (j + 1 < j1) {
                acc.x += fmaxf(hB.x + mB.x, 0.0f);
                acc.y += fmaxf(hB.y + mB.y, 0.0f);
            }
            A0 = C0; A1 = C1; A2 = C2; A3 = C3; hA = hC;
            B0 = D0; B1 = D1; B2 = D2; B3 = D3; hB = hD;
        }
    }
    float* dstp = (half ? aggr3 : aggr2) + (size_t)n * 64 + co;
    *(float2*)dstp = acc;
}

// ===========================================================================
// Node MLP: out = epilogue( relu((xin+aggr) @ Wa + ba) @ Wb + bb )
// KIN -> 64 -> 64. 64 nodes per block, 256 threads, 4x4 register tiles.
// mode: 0 = none, 1 = relu, 2 = clip(-10, 10)
// ===========================================================================
template <int KIN>
__global__ __launch_bounds__(256) void node_mlp(
    const float* __restrict__ xin, const float* __restrict__ aggr,
    const float* __restrict__ Wa, const float* __restrict__ ba,
    const float* __restrict__ Wb, const float* __restrict__ bb,
    float* __restrict__ out, int mode)
{
    constexpr int S0 = KIN + 4;
    constexpr int K4 = KIN / 4;
    __shared__ float sWa[KIN * 64];
    __shared__ float sWb[64 * 64];
    __shared__ float sh[64 * S0];
    __shared__ float sba[64], sbb[64];
    int t = threadIdx.x;
    for (int i = t; i < KIN * 16; i += 256) ((float4*)sWa)[i] = ((const float4*)Wa)[i];
    for (int i = t; i < 1024; i += 256)     ((float4*)sWb)[i] = ((const float4*)Wb)[i];
    if (t < 64) { sba[t] = ba[t]; sbb[t] = bb[t]; }

    int nb = blockIdx.x << 6;
    for (int i = t; i < 64 * K4; i += 256) {
        int n = i / K4, k4 = i % K4;
        int node = nb + n;
        float4 v = make_float4(0.f, 0.f, 0.f, 0.f);
        if (node < NN) {
            float4 a = ((const float4*)(xin  + (size_t)node * KIN))[k4];
            float4 b = ((const float4*)(aggr + (size_t)node * KIN))[k4];
            v = make_float4(a.x + b.x, a.y + b.y, a.z + b.z, a.w + b.w);
        }
        *(float4*)&sh[n * S0 + (k4 << 2)] = v;
    }
    __syncthreads();

    int tx = t & 15, ty = t >> 4;
    int c0 = tx << 2, n0 = ty << 2;

    float4 b1 = *(const float4*)&sba[c0];
    float acc[4][4];
    #pragma unroll
    for (int i = 0; i < 4; i++) { acc[i][0] = b1.x; acc[i][1] = b1.y; acc[i][2] = b1.z; acc[i][3] = b1.w; }
    for (int k4 = 0; k4 < K4; k4++) {
        int k = k4 << 2;
        float4 w0 = *(const float4*)&sWa[((k + 0) << 6) + c0];
        float4 w1 = *(const float4*)&sWa[((k + 1) << 6) + c0];
        float4 w2 = *(const float4*)&sWa[((k + 2) << 6) + c0];
        float4 w3 = *(const float4*)&sWa[((k + 3) << 6) + c0];
        #pragma unroll
        for (int i = 0; i < 4; i++) {
            float4 hv = *(const float4*)&sh[(n0 + i) * S0 + k];
            acc[i][0] = fmaf(hv.x, w0.x, acc[i][0]); acc[i][1] = fmaf(hv.x, w0.y, acc[i][1]);
            acc[i][2] = fmaf(hv.x, w0.z, acc[i][2]); acc[i][3] = fmaf(hv.x, w0.w, acc[i][3]);
            acc[i][0] = fmaf(hv.y, w1.x, acc[i][0]); acc[i][1] = fmaf(hv.y, w1.y, acc[i][1]);
            acc[i][2] = fmaf(hv.y, w1.z, acc[i][2]); acc[i][3] = fmaf(hv.y, w1.w, acc[i][3]);
            acc[i][0] = fmaf(hv.z, w2.x, acc[i][0]); acc[i][1] = fmaf(hv.z, w2.y, acc[i][1]);
            acc[i][2] = fmaf(hv.z, w2.z, acc[i][2]); acc[i][3] = fmaf(hv.z, w2.w, acc[i][3]);
            acc[i][0] = fmaf(hv.w, w3.x, acc[i][0]); acc[i][1] = fmaf(hv.w, w3.y, acc[i][1]);
            acc[i][2] = fmaf(hv.w, w3.z, acc[i][2]); acc[i][3] = fmaf(hv.w, w3.w, acc[i][3]);
        }
    }
    __syncthreads();
    #pragma unroll
    for (int i = 0; i < 4; i++) {
        float4 v = make_float4(fmaxf(acc[i][0], 0.f), fmaxf(acc[i][1], 0.f),
                               fmaxf(acc[i][2], 0.f), fmaxf(acc[i][3], 0.f));
        *(float4*)&sh[(n0 + i) * 68 + c0] = v;
    }
    __syncthreads();

    float4 b2 = *(const float4*)&sbb[c0];
    float acc2[4][4];
    #pragma unroll
    for (int i = 0; i < 4; i++) { acc2[i][0] = b2.x; acc2[i][1] = b2.y; acc2[i][2] = b2.z; acc2[i][3] = b2.w; }
    for (int k4 = 0; k4 < 16; k4++) {
        int k = k4 << 2;
        float4 w0 = *(const float4*)&sWb[((k + 0) << 6) + c0];
        float4 w1 = *(const float4*)&sWb[((k + 1) << 6) + c0];
        float4 w2 = *(const float4*)&sWb[((k + 2) << 6) + c0];
        float4 w3 = *(const float4*)&sWb[((k + 3) << 6) + c0];
        #pragma unroll
        for (int i = 0; i < 4; i++) {
            float4 hv = *(const float4*)&sh[(n0 + i) * 68 + k];
            acc2[i][0] = fmaf(hv.x, w0.x, acc2[i][0]); acc2[i][1] = fmaf(hv.x, w0.y, acc2[i][1]);
            acc2[i][2] = fmaf(hv.x, w0.z, acc2[i][2]); acc2[i][3] = fmaf(hv.x, w0.w, acc2[i][3]);
            acc2[i][0] = fmaf(hv.y, w1.x, acc2[i][0]); acc2[i][1] = fmaf(hv.y, w1.y, acc2[i][1]);
            acc2[i][2] = fmaf(hv.y, w1.z, acc2[i][2]); acc2[i][3] = fmaf(hv.y, w1.w, acc2[i][3]);
            acc2[i][0] = fmaf(hv.z, w2.x, acc2[i][0]); acc2[i][1] = fmaf(hv.z, w2.y, acc2[i][1]);
            acc2[i][2] = fmaf(hv.z, w2.z, acc2[i][2]); acc2[i][3] = fmaf(hv.z, w2.w, acc2[i][3]);
            acc2[i][0] = fmaf(hv.w, w3.x, acc2[i][0]); acc2[i][1] = fmaf(hv.w, w3.y, acc2[i][1]);
            acc2[i][2] = fmaf(hv.w, w3.z, acc2[i][2]); acc2[i][3] = fmaf(hv.w, w3.w, acc2[i][3]);
        }
    }

    #pragma unroll
    for (int i = 0; i < 4; i++) {
        int node = nb + n0 + i;
        if (node >= NN) continue;
        float4 v = make_float4(acc2[i][0], acc2[i][1], acc2[i][2], acc2[i][3]);
        if (mode == 1) {
            v = make_float4(fmaxf(v.x, 0.f), fmaxf(v.y, 0.f), fmaxf(v.z, 0.f), fmaxf(v.w, 0.f));
        } else if (mode == 2) {
            v = make_float4(fminf(fmaxf(v.x, -10.f), 10.f), fminf(fmaxf(v.y, -10.f), 10.f),
                            fminf(fmaxf(v.z, -10.f), 10.f), fminf(fmaxf(v.w, -10.f), 10.f));
        }
        *(float4*)(out + (size_t)node * 64 + c0) = v;
    }
}

extern "C" void kernel_launch(void* const* d_in, const int* in_sizes, int n_in,
                              void* d_out, int out_size, void* d_ws, size_t ws_size,
                              hipStream_t stream)
{
    const float* x   = (const float*)d_in[0];
    const int*   ei  = (const int*)  d_in[1];
    const float* ea  = (const float*)d_in[2];
    const float* We1 = (const float*)d_in[3];
    const float* be1 = (const float*)d_in[4];
    const float* W1a = (const float*)d_in[5];
    const float* b1a = (const float*)d_in[6];
    const float* W1b = (const float*)d_in[7];
    const float* b1b = (const float*)d_in[8];
    const float* We2 = (const float*)d_in[9];
    const float* be2 = (const float*)d_in[10];
    const float* W2a = (const float*)d_in[11];
    const float* b2a = (const float*)d_in[12];
    const float* W2b = (const float*)d_in[13];
    const float* b2b = (const float*)d_in[14];
    const float* We3 = (const float*)d_in[15];
    const float* be3 = (const float*)d_in[16];
    const float* W3a = (const float*)d_in[17];
    const float* b3a = (const float*)d_in[18];
    const float* W3b = (const float*)d_in[19];
    const float* b3b = (const float*)d_in[20];

    float* out = (float*)d_out;
    float* ws = (float*)d_ws;
    // float scratch: aggr1 [12.8M] (later aliased by aggr2/aggr3), h [6.4M]
    float* aggr1 = ws;
    float* h     = ws + 12800000;
    float* aggr2 = ws;              // aliases aggr1 (dead after node_mlp<128>)
    float* aggr3 = ws + 6400000;
    // int scratch after 19.2M floats: off [NN+1], cur [NN], perm2 [2*NE]
    int* ibase = (int*)(ws + 19200000);
    int* off   = ibase;
    int* cur   = ibase + (NN + 1);
    int2* perm2 = (int2*)(ibase + (2 * NN + 2));
    // 98 block sums live in the (currently idle) aggr3 float region —
    // CSR build completes before any conv kernel touches aggr3.
    int* bsum  = (int*)(ws + 6400000);

    // ---- CSR build (shared by conv1 and conv23) ----
    hipMemsetAsync(cur, 0, (size_t)NN * sizeof(int), stream);
    hist_dst<<<2048, 256, 0, stream>>>(ei, cur);
    deg_block_sum<<<NBLK, 1024, 0, stream>>>(cur, bsum);
    scan_bsum<<<1, 128, 0, stream>>>(bsum, off);
    deg_block_scan<<<NBLK, 1024, 0, stream>>>(cur, off, bsum); // cur -> cursor
    scatter_perm<<<2048, 256, 0, stream>>>(ei, cur, perm2);

    // ---- layer 1 ----
    conv1_gather<<<(NN + 3) / 4, 256, 0, stream>>>(x, ea, We1, be1, off, perm2, aggr1);
    node_mlp<128><<<(NN + 63) / 64, 256, 0, stream>>>(x, aggr1, W1a, b1a, W1b, b1b, h, 1);

    // ---- layers 2+3 (fused edge pass) ----
    conv23_gather<<<(NN + 3) / 4, 256, 0, stream>>>(h, ea, We2, be2, We3, be3,
                                                    off, perm2, aggr2, aggr3);
    node_mlp<64><<<(NN + 63) / 64, 256, 0, stream>>>(h, aggr2, W2a, b2a, W2b, b2b, out, 0);
    node_mlp<64><<<(NN + 63) / 64, 256, 0, stream>>>(h, aggr3, W3a, b3a, W3b, b3b,
                                                     out + (size_t)NN * 64, 2);
}